// Round 4
// baseline (1081.522 us; speedup 1.0000x reference)
//
#include <hip/hip_runtime.h>
#include <hip/hip_bf16.h>
#include <stdint.h>

// ProjSolver R4: one fused dispatch per iteration computes z(t-1) @ [Wz; A]^T
// (N = 2048 znew cols + 1024 resid cols) in 128x64 block tiles, 2 waves/block,
// each wave a 64x64 quadrant with 4x4 16x16x32 bf16 MFMA frags (m97 interior:
// 8 ds_read_b128 + 16 MFMA per wave-K-tile). Grid 48x16 = 768 blocks = 6
// waves/CU. Resid columns reduce via atomicMax; last resid block updates
// done/iters in-kernel (ticket). z-chain ping-pongs; k_final picks buffer.

typedef __hip_bfloat16 bf16;
typedef __attribute__((ext_vector_type(8))) short short8;
typedef __attribute__((ext_vector_type(4))) float f32x4;

#define N_DIM 2048
#define K_DIM 2048
#define MRES  1024
#define FREE_NUM 1024
#define NTOT (2048*2048)
#define F_TOL 1e-6f
#define MAX_ITER 16
#define NRB 256   // resid blocks: 16 x-tiles * 16 y-tiles

__device__ __forceinline__ void async_cp16(const void* g, void* l) {
  __builtin_amdgcn_global_load_lds(
      (const __attribute__((address_space(1))) unsigned int*)g,
      (__attribute__((address_space(3))) unsigned int*)l, 16, 0, 0);
}

// flags: [0]=res max bits, [1]=done, [2]=iters, [3]=ticket
__global__ void k_init(unsigned* f) { f[0]=0u; f[1]=0u; f[2]=0u; f[3]=0u; }

__global__ __launch_bounds__(256) void k_cast(
    const float* __restrict__ in, bf16* __restrict__ o, int n)
{
  int i = (blockIdx.x * 256 + threadIdx.x) * 4;
  if (i < n) {
    float4 v = *(const float4*)(in + i);
    o[i + 0] = __float2bfloat16(v.x);
    o[i + 1] = __float2bfloat16(v.y);
    o[i + 2] = __float2bfloat16(v.z);
    o[i + 3] = __float2bfloat16(v.w);
  }
}

__global__ __launch_bounds__(256) void k_bias(
    const float* __restrict__ b, const float* __restrict__ Wb,
    float* __restrict__ bias)
{
  const int j = blockIdx.x;
  const int tid = threadIdx.x;
  float s = 0.f;
  for (int m = tid; m < MRES; m += 256)
    s += b[m] * Wb[(size_t)j * MRES + m];
#pragma unroll
  for (int off = 32; off > 0; off >>= 1) s += __shfl_xor(s, off);
  __shared__ float red[4];
  const int w = tid >> 6, l = tid & 63;
  if (l == 0) red[w] = s;
  __syncthreads();
  if (tid == 0) bias[j] = red[0] + red[1] + red[2] + red[3];
}

// ---------------- fused step: C = Zin @ [Wz; A]^T, 128x64 tiles, 2 waves -----
__global__ __launch_bounds__(128, 2) void k_step(
    const bf16* __restrict__ Zin, const bf16* __restrict__ Wzb,
    const bf16* __restrict__ Ab, const float* __restrict__ bias,
    const float* __restrict__ bvec, bf16* __restrict__ Zout,
    unsigned* __restrict__ flags, int consume)
{
  __shared__ __align__(16) short sA[128 * 32];   // 8 KB
  __shared__ __align__(16) short sB[64 * 32];    // 4 KB
  __shared__ unsigned s_done;
  __shared__ float wred[2];
  __shared__ unsigned s_last;

  const int tid = threadIdx.x;
  if (tid == 0) s_done = flags[1];
  const int w = tid >> 6, l = tid & 63;          // 2 waves
  const int q = l >> 4, lm = l & 15;
  const int rowBase = blockIdx.y * 128;
  const int colBase = blockIdx.x * 64;
  const bool isZ = colBase < N_DIM;
  __syncthreads();
  const unsigned done0 = s_done;

  float mx = 0.f;
  if (!done0) {
    const bf16* Bp = isZ ? (Wzb + (size_t)colBase * K_DIM)
                         : (Ab + (size_t)(colBase - N_DIM) * K_DIM);
    f32x4 acc[4][4];
    f32x4 zero4 = {0.f, 0.f, 0.f, 0.f};
#pragma unroll
    for (int i = 0; i < 4; i++)
#pragma unroll
      for (int j = 0; j < 4; j++) acc[i][j] = zero4;

    for (int k0 = 0; k0 < K_DIM; k0 += 32) {
      // sA: 128x32 = 512 16B-chunks; sB: 64x32 = 256 chunks. 6 chunks/thread.
#pragma unroll
      for (int r = 0; r < 4; r++) {
        int c = tid + 128 * r;                // 0..511
        int row = c >> 2, kc = c & 3;
        async_cp16(Zin + (size_t)(rowBase + row) * K_DIM + k0 + kc * 8, sA + c * 8);
      }
#pragma unroll
      for (int r = 0; r < 2; r++) {
        int c = tid + 128 * r;                // 0..255
        int row = c >> 2, kc = c & 3;
        async_cp16(Bp + (size_t)row * K_DIM + k0 + kc * 8, sB + c * 8);
      }
      __syncthreads();
      short8 af[4], bfr[4];
#pragma unroll
      for (int mr = 0; mr < 4; mr++)
        af[mr] = *(const short8*)(sA + (w * 64 + mr * 16 + lm) * 32 + q * 8);
#pragma unroll
      for (int nc = 0; nc < 4; nc++)
        bfr[nc] = *(const short8*)(sB + (nc * 16 + lm) * 32 + q * 8);
#pragma unroll
      for (int mr = 0; mr < 4; mr++)
#pragma unroll
        for (int nc = 0; nc < 4; nc++)
          acc[mr][nc] = __builtin_amdgcn_mfma_f32_16x16x32_bf16(
              af[mr], bfr[nc], acc[mr][nc], 0, 0, 0);
      __syncthreads();
    }

    if (isZ) {
#pragma unroll
      for (int mr = 0; mr < 4; mr++) {
#pragma unroll
        for (int nc = 0; nc < 4; nc++) {
          int gc = colBase + nc * 16 + lm;
          int gr0 = rowBase + w * 64 + mr * 16 + q * 4;
          float bv = bias[gc];
#pragma unroll
          for (int r = 0; r < 4; r++) {
            float v = acc[mr][nc][r] + bv;
            if (gc >= FREE_NUM) v = fmaxf(v, 0.f);
            Zout[(size_t)(gr0 + r) * N_DIM + gc] = __float2bfloat16(v);
          }
        }
      }
    } else {
#pragma unroll
      for (int mr = 0; mr < 4; mr++) {
#pragma unroll
        for (int nc = 0; nc < 4; nc++) {
          int rc = colBase - N_DIM + nc * 16 + lm;
          float bv = bvec[rc];
#pragma unroll
          for (int r = 0; r < 4; r++)
            mx = fmaxf(mx, fabsf(acc[mr][nc][r] - bv));
        }
      }
    }
  }

  if (!isZ) {
#pragma unroll
    for (int off = 32; off > 0; off >>= 1) mx = fmaxf(mx, __shfl_xor(mx, off));
    if (l == 0) wred[w] = mx;
    __syncthreads();
    if (tid == 0) {
      if (!done0) {
        float m2 = fmaxf(wred[0], wred[1]);
        atomicMax(flags, __float_as_uint(m2));  // values non-negative
      }
      __threadfence();
      unsigned tk = atomicAdd(flags + 3, 1u);
      s_last = (tk == NRB - 1) ? 1u : 0u;
    }
    __syncthreads();
    if (s_last && tid == 0) {
      unsigned rb = atomicMax(flags, 0u);       // coherent read of res max
      float res = __uint_as_float(rb);
      if (consume && flags[1] == 0u) {
        flags[2] += 1u;                          // iters++ for iteration t-1
        if (res <= F_TOL) flags[1] = 1u;         // done latch
      }
      flags[0] = 0u;
      flags[3] = 0u;
      __threadfence();
    }
  }
}

__global__ __launch_bounds__(256) void k_final(
    const bf16* __restrict__ z0, const bf16* __restrict__ z1,
    const unsigned* __restrict__ flags, float* __restrict__ out)
{
  size_t i = (size_t)blockIdx.x * 256 + threadIdx.x;
  unsigned done = flags[1], iters = flags[2];
  const bf16* src = done ? ((iters & 1u) ? z1 : z0) : z0;
  if (i < NTOT) out[i] = __bfloat162float(src[i]);
  else if (i == NTOT) out[i] = (float)(iters + (done ? 0u : 1u) + 1u);
}

// ---------------- launcher ----------------------------------------------------
extern "C" void kernel_launch(void* const* d_in, const int* in_sizes, int n_in,
                              void* d_out, int out_size, void* d_ws, size_t ws_size,
                              hipStream_t stream) {
  const float* z  = (const float*)d_in[0];
  const float* b  = (const float*)d_in[1];
  const float* A  = (const float*)d_in[2];
  const float* Wz = (const float*)d_in[3];
  const float* Wb = (const float*)d_in[4];
  float* out = (float*)d_out;

  // bf16 weights parked in d_out bytes (overwritten by k_final at the end)
  bf16* Wzb = (bf16*)d_out;                 // 8 MB
  bf16* Ab  = Wzb + (size_t)NTOT;           // 4 MB

  char* ws = (char*)d_ws;                   // ~16.01 MB used
  unsigned* flags = (unsigned*)ws;
  float* bias = (float*)(ws + 256);
  bf16* buf0 = (bf16*)(ws + 256 + 2048 * sizeof(float));
  bf16* buf1 = buf0 + (size_t)NTOT;

  k_init<<<1, 1, 0, stream>>>(flags);
  k_cast<<<NTOT / 1024, 256, 0, stream>>>(Wz, Wzb, NTOT);
  k_cast<<<(MRES * N_DIM) / 1024, 256, 0, stream>>>(A, Ab, MRES * N_DIM);
  k_cast<<<NTOT / 1024, 256, 0, stream>>>(z, buf0, NTOT);   // z(0) -> buf0
  k_bias<<<N_DIM, 256, 0, stream>>>(b, Wb, bias);

  for (int t = 1; t <= MAX_ITER; t++) {
    const bf16* in = ((t - 1) & 1) ? buf1 : buf0;   // z(t-1)
    bf16* o = (t & 1) ? buf1 : buf0;                // z(t)
    k_step<<<dim3(48, 16), 128, 0, stream>>>(in, Wzb, Ab, bias, b, o, flags,
                                             (t >= 2) ? 1 : 0);
  }
  k_final<<<(NTOT + 256) / 256 + 1, 256, 0, stream>>>(buf0, buf1, flags, out);
}

// Round 5
// 750.403 us; speedup vs baseline: 1.4413x; 1.4413x over previous
//
#include <hip/hip_runtime.h>
#include <hip/hip_bf16.h>
#include <stdint.h>

// ProjSolver R5: fused step kernel (znew + resid columns) with
//  (a) double-buffered LDS staging: loads for K-tile k+1 issued right after
//      the barrier that publishes tile k -> global latency overlapped with
//      the 8 ds_read_b128 + 16 MFMA compute phase (single barrier/iter).
//  (b) XOR bank swizzle on 16B chunks (slot = kc ^ ((row>>1)&3)), applied to
//      the per-lane GLOBAL address at staging (LDS side must stay
//      lane-contiguous for global_load_lds) and mirrored at ds_read time.
// Block: 128 thr / 2 waves, tile 128x64, wave-tile 64x64 (4x4 16x16x32 bf16).
// Grid 48x16 = 768 blocks. Resid columns (colBase>=2048) reduce max|.-b| via
// atomicMax; last resid block (ticket) updates done/iters in-kernel.

typedef __hip_bfloat16 bf16;
typedef __attribute__((ext_vector_type(8))) short short8;
typedef __attribute__((ext_vector_type(4))) float f32x4;

#define N_DIM 2048
#define K_DIM 2048
#define MRES  1024
#define FREE_NUM 1024
#define NTOT (2048*2048)
#define F_TOL 1e-6f
#define MAX_ITER 16
#define NRB 256   // resid blocks: 16 x-tiles * 16 y-tiles

__device__ __forceinline__ void async_cp16(const void* g, void* l) {
  __builtin_amdgcn_global_load_lds(
      (const __attribute__((address_space(1))) unsigned int*)g,
      (__attribute__((address_space(3))) unsigned int*)l, 16, 0, 0);
}

// flags: [0]=res max bits, [1]=done, [2]=iters, [3]=ticket
__global__ void k_init(unsigned* f) { f[0]=0u; f[1]=0u; f[2]=0u; f[3]=0u; }

__global__ __launch_bounds__(256) void k_cast(
    const float* __restrict__ in, bf16* __restrict__ o, int n)
{
  int i = (blockIdx.x * 256 + threadIdx.x) * 4;
  if (i < n) {
    float4 v = *(const float4*)(in + i);
    o[i + 0] = __float2bfloat16(v.x);
    o[i + 1] = __float2bfloat16(v.y);
    o[i + 2] = __float2bfloat16(v.z);
    o[i + 3] = __float2bfloat16(v.w);
  }
}

__global__ __launch_bounds__(256) void k_bias(
    const float* __restrict__ b, const float* __restrict__ Wb,
    float* __restrict__ bias)
{
  const int j = blockIdx.x;
  const int tid = threadIdx.x;
  float s = 0.f;
  for (int m = tid; m < MRES; m += 256)
    s += b[m] * Wb[(size_t)j * MRES + m];
#pragma unroll
  for (int off = 32; off > 0; off >>= 1) s += __shfl_xor(s, off);
  __shared__ float red[4];
  const int w = tid >> 6, l = tid & 63;
  if (l == 0) red[w] = s;
  __syncthreads();
  if (tid == 0) bias[j] = red[0] + red[1] + red[2] + red[3];
}

// ---------------- fused step: C = Zin @ [Wz; A]^T ----------------------------
__global__ __launch_bounds__(128, 2) void k_step(
    const bf16* __restrict__ Zin, const bf16* __restrict__ Wzb,
    const bf16* __restrict__ Ab, const float* __restrict__ bias,
    const float* __restrict__ bvec, bf16* __restrict__ Zout,
    unsigned* __restrict__ flags, int consume)
{
  __shared__ __align__(16) short sA[2][128 * 32];   // 2 x 8 KB
  __shared__ __align__(16) short sB[2][64 * 32];    // 2 x 4 KB
  __shared__ unsigned s_done;
  __shared__ float wred[2];
  __shared__ unsigned s_last;

  const int tid = threadIdx.x;
  if (tid == 0) s_done = flags[1];
  const int w = tid >> 6, l = tid & 63;             // 2 waves
  const int q = l >> 4, lm = l & 15;
  const int sw = (lm >> 1) & 3;                     // read-side swizzle key
  const int rowBase = blockIdx.y * 128;
  const int colBase = blockIdx.x * 64;
  const bool isZ = colBase < N_DIM;
  __syncthreads();
  const unsigned done0 = s_done;

  float mx = 0.f;
  if (!done0) {
    const bf16* Bp = isZ ? (Wzb + (size_t)colBase * K_DIM)
                         : (Ab + (size_t)(colBase - N_DIM) * K_DIM);
    f32x4 acc[4][4];
    f32x4 zero4 = {0.f, 0.f, 0.f, 0.f};
#pragma unroll
    for (int i = 0; i < 4; i++)
#pragma unroll
      for (int j = 0; j < 4; j++) acc[i][j] = zero4;

    // stage one 128x32 A-tile + 64x32 B-tile into buffer p, chunk-swizzled.
    // LDS side: chunk c at byte c*16 (lane-contiguous, required by
    // global_load_lds). Global side: row = c>>2, slot = c&3,
    // source chunk kc = slot ^ ((row>>1)&3).
    auto stage = [&](int k0, int p) {
      short* sAp = sA[p];
      short* sBp = sB[p];
#pragma unroll
      for (int r = 0; r < 4; r++) {                 // 512 A-chunks, 4/thread
        int c = tid + 128 * r;
        int row = c >> 2, sl = c & 3;
        int kc = sl ^ ((row >> 1) & 3);
        async_cp16(Zin + (size_t)(rowBase + row) * K_DIM + k0 + kc * 8,
                   sAp + c * 8);
      }
#pragma unroll
      for (int r = 0; r < 2; r++) {                 // 256 B-chunks, 2/thread
        int c = tid + 128 * r;
        int row = c >> 2, sl = c & 3;
        int kc = sl ^ ((row >> 1) & 3);
        async_cp16(Bp + (size_t)row * K_DIM + k0 + kc * 8, sBp + c * 8);
      }
    };

    stage(0, 0);
#pragma unroll 2
    for (int kk = 0; kk < 32; kk++) {
      const int cur = kk & 1;
      // Barrier (compiler drains vmcnt here): publishes tile `cur`, and
      // guarantees everyone finished computing from tile cur^1.
      __syncthreads();
      if (kk < 31) stage((kk + 1) * 32, cur ^ 1);   // in-flight during compute
      const short* sAc = sA[cur];
      const short* sBc = sB[cur];
      short8 af[4], bfr[4];
#pragma unroll
      for (int mr = 0; mr < 4; mr++) {
        int R = w * 64 + mr * 16 + lm;
        af[mr] = *(const short8*)(sAc + (R * 4 + (q ^ sw)) * 8);
      }
#pragma unroll
      for (int nc = 0; nc < 4; nc++) {
        int Rb = nc * 16 + lm;
        bfr[nc] = *(const short8*)(sBc + (Rb * 4 + (q ^ sw)) * 8);
      }
#pragma unroll
      for (int mr = 0; mr < 4; mr++)
#pragma unroll
        for (int nc = 0; nc < 4; nc++)
          acc[mr][nc] = __builtin_amdgcn_mfma_f32_16x16x32_bf16(
              af[mr], bfr[nc], acc[mr][nc], 0, 0, 0);
    }

    if (isZ) {
#pragma unroll
      for (int mr = 0; mr < 4; mr++) {
#pragma unroll
        for (int nc = 0; nc < 4; nc++) {
          int gc = colBase + nc * 16 + lm;
          int gr0 = rowBase + w * 64 + mr * 16 + q * 4;
          float bv = bias[gc];
#pragma unroll
          for (int r = 0; r < 4; r++) {
            float v = acc[mr][nc][r] + bv;
            if (gc >= FREE_NUM) v = fmaxf(v, 0.f);
            Zout[(size_t)(gr0 + r) * N_DIM + gc] = __float2bfloat16(v);
          }
        }
      }
    } else {
#pragma unroll
      for (int mr = 0; mr < 4; mr++) {
#pragma unroll
        for (int nc = 0; nc < 4; nc++) {
          int rc = colBase - N_DIM + nc * 16 + lm;
          float bv = bvec[rc];
#pragma unroll
          for (int r = 0; r < 4; r++)
            mx = fmaxf(mx, fabsf(acc[mr][nc][r] - bv));
        }
      }
    }
  }

  if (!isZ) {
#pragma unroll
    for (int off = 32; off > 0; off >>= 1) mx = fmaxf(mx, __shfl_xor(mx, off));
    if (l == 0) wred[w] = mx;
    __syncthreads();
    if (tid == 0) {
      if (!done0) {
        float m2 = fmaxf(wred[0], wred[1]);
        atomicMax(flags, __float_as_uint(m2));  // values non-negative
      }
      __threadfence();
      unsigned tk = atomicAdd(flags + 3, 1u);
      s_last = (tk == NRB - 1) ? 1u : 0u;
    }
    __syncthreads();
    if (s_last && tid == 0) {
      unsigned rb = atomicMax(flags, 0u);       // coherent read of res max
      float res = __uint_as_float(rb);
      if (consume && flags[1] == 0u) {
        flags[2] += 1u;                          // iters++ for iteration t-1
        if (res <= F_TOL) flags[1] = 1u;         // done latch
      }
      flags[0] = 0u;
      flags[3] = 0u;
      __threadfence();
    }
  }
}

__global__ __launch_bounds__(256) void k_final(
    const bf16* __restrict__ z0, const bf16* __restrict__ z1,
    const unsigned* __restrict__ flags, float* __restrict__ out)
{
  size_t i = (size_t)blockIdx.x * 256 + threadIdx.x;
  unsigned done = flags[1], iters = flags[2];
  const bf16* src = done ? ((iters & 1u) ? z1 : z0) : z0;
  if (i < NTOT) out[i] = __bfloat162float(src[i]);
  else if (i == NTOT) out[i] = (float)(iters + (done ? 0u : 1u) + 1u);
}

// ---------------- launcher ----------------------------------------------------
extern "C" void kernel_launch(void* const* d_in, const int* in_sizes, int n_in,
                              void* d_out, int out_size, void* d_ws, size_t ws_size,
                              hipStream_t stream) {
  const float* z  = (const float*)d_in[0];
  const float* b  = (const float*)d_in[1];
  const float* A  = (const float*)d_in[2];
  const float* Wz = (const float*)d_in[3];
  const float* Wb = (const float*)d_in[4];
  float* out = (float*)d_out;

  // bf16 weights parked in d_out bytes (overwritten by k_final at the end)
  bf16* Wzb = (bf16*)d_out;                 // 8 MB
  bf16* Ab  = Wzb + (size_t)NTOT;           // 4 MB

  char* ws = (char*)d_ws;                   // ~16.01 MB used
  unsigned* flags = (unsigned*)ws;
  float* bias = (float*)(ws + 256);
  bf16* buf0 = (bf16*)(ws + 256 + 2048 * sizeof(float));
  bf16* buf1 = buf0 + (size_t)NTOT;

  k_init<<<1, 1, 0, stream>>>(flags);
  k_cast<<<NTOT / 1024, 256, 0, stream>>>(Wz, Wzb, NTOT);
  k_cast<<<(MRES * N_DIM) / 1024, 256, 0, stream>>>(A, Ab, MRES * N_DIM);
  k_cast<<<NTOT / 1024, 256, 0, stream>>>(z, buf0, NTOT);   // z(0) -> buf0
  k_bias<<<N_DIM, 256, 0, stream>>>(b, Wb, bias);

  for (int t = 1; t <= MAX_ITER; t++) {
    const bf16* in = ((t - 1) & 1) ? buf1 : buf0;   // z(t-1)
    bf16* o = (t & 1) ? buf1 : buf0;                // z(t)
    k_step<<<dim3(48, 16), 128, 0, stream>>>(in, Wzb, Ab, bias, b, o, flags,
                                             (t >= 2) ? 1 : 0);
  }
  k_final<<<(NTOT + 256) / 256 + 1, 256, 0, stream>>>(buf0, buf1, flags, out);
}